// Round 9
// baseline (760.408 us; speedup 1.0000x reference)
//
#include <hip/hip_runtime.h>
#include <math.h>

typedef unsigned short ushort;
typedef unsigned int   uint;
typedef short bf16x8 __attribute__((ext_vector_type(8)));
typedef float f32x4  __attribute__((ext_vector_type(4)));
typedef ushort u16x8 __attribute__((ext_vector_type(8)));
typedef ushort u16x4 __attribute__((ext_vector_type(4)));

// ---------------- problem constants ----------------
#define N_ENTS   50000
#define E_EDGES  800000
#define HD       128
#define BSZ      1024
#define C_CH     96
#define FLATD    9600
#define TOPK_K   15
#define HIDD     200
#define SPLITK   10
#define OUT_SCORE ((size_t)BSZ * N_ENTS)

#define MPAD     50048            // 391*128
#define NPAD_ENT 50176            // 196*256
#define KPAD200  224
#define NPAD200  256
#define L2E      1.4426950408889634f
#define SCAP     512              // max in-degree supported by k_edge LDS (input max ~45)

// ---------------- workspace layout (byte offsets) ----------------
#define OFF_EP       ((size_t)0)            // ushort [50048][256] interleaved c/p (c1/c2 alias later)
#define OFF_ENTOUT   ((size_t)25624576)     // ushort [50176][128]
#define OFF_RELBF    ((size_t)38469632)     // ushort [1000][128]
#define OFF_PRELBF   ((size_t)38725632)
#define OFF_SWT      ((size_t)38981632)     // ushort [128][128]
#define OFF_LWT      ((size_t)39014400)
#define OFF_NWT      ((size_t)39047168)
#define OFF_P0T      ((size_t)39079936)     // ushort [256][128]
#define OFF_Q0T      ((size_t)39145472)
#define OFF_P1T      ((size_t)39211008)     // ushort [256][224]
#define OFF_Q1T      ((size_t)39325696)
#define OFF_FCT      ((size_t)39440384)     // ushort [128][9600]
#define OFF_SIDX     ((size_t)54697984)     // int4 [800000]
#define OFF_DEG      ((size_t)70697984)     // int [50000]
#define OFF_START    ((size_t)70897984)
#define OFF_CUR      ((size_t)71097984)
#define OFF_BSUM     ((size_t)71297984)     // int [1024]
#define OFF_X1       ((size_t)71302080)     // float [50000]
#define OFF_X2       ((size_t)71502080)
#define OFF_XFC      ((size_t)71702336)     // ushort [1024][128]
#define OFF_ARENA    ((size_t)71964480)
// arena: ent_bf=+0 (u16[50048][128]) [dead after proj]
//        neigh1=+0, neigh2=+12812288 [dead after k_tanh2ent]
//        convout=+0 (u16[1024][9600]), fcpart=+22421504 (f32[10][1024][128])
// c1 = EP+0 (u16[50048][128]), c2 = EP+12812288  (EP dead after k_edge)

// ---------------- helpers ----------------
__device__ inline ushort f2b(float f) {
    uint u = __float_as_uint(f);
    return (ushort)((u + 0x7fffu + ((u >> 16) & 1u)) >> 16);  // RNE
}
__device__ inline float b2f(ushort u) { return __uint_as_float((uint)u << 16); }
__device__ inline float fexp2(float x) { return __builtin_amdgcn_exp2f(x); }
__device__ inline float frcp(float x)  { return __builtin_amdgcn_rcpf(x); }
__device__ inline float fsigmoid(float x) { return frcp(1.f + fexp2(-x * L2E)); }
__device__ inline float ftanh(float x) {
    float ax = fabsf(x);
    float t = fexp2(ax * (-2.f * L2E));
    float r = (1.f - t) * frcp(1.f + t);
    return copysignf(r, x);
}

// ---------------- conversion kernels ----------------
__global__ void k_cvt(const float* __restrict__ in, ushort* __restrict__ out,
                      int M, int Mpad, int K) {
    int i = blockIdx.x * 256 + threadIdx.x;
    if (i >= Mpad * K) return;
    int r = i / K;
    out[i] = (r < M) ? f2b(in[i]) : (ushort)0;
}

__global__ void k_cvt2(const float* __restrict__ in0, ushort* __restrict__ out0,
                       const float* __restrict__ in1, ushort* __restrict__ out1, int n) {
    const float* in = blockIdx.z ? in1 : in0;
    ushort* out = blockIdx.z ? out1 : out0;
    int i = blockIdx.x * 256 + threadIdx.x;
    if (i < n) out[i] = f2b(in[i]);
}

__global__ __launch_bounds__(256) void k_tcvtT(const float* __restrict__ in, ushort* __restrict__ out,
                                               int K, int N, int Kpad, int Npad) {
    __shared__ float t[32][33];
    int k0 = blockIdx.x * 32, n0 = blockIdx.y * 32;
    int tx = threadIdx.x & 31, ty = threadIdx.x >> 5;
    for (int i = ty; i < 32; i += 8) {
        int k = k0 + i, n = n0 + tx;
        t[i][tx] = (k < K && n < N) ? in[(size_t)k * N + n] : 0.f;
    }
    __syncthreads();
    for (int i = ty; i < 32; i += 8) {
        int n = n0 + i, k = k0 + tx;
        if (n < Npad && k < Kpad) out[(size_t)n * Kpad + k] = f2b(t[tx][i]);
    }
}

__global__ __launch_bounds__(256) void k_tcvt7(
    const float* __restrict__ S_w, const float* __restrict__ L_w, const float* __restrict__ n_w,
    const float* __restrict__ p0, const float* __restrict__ q0,
    const float* __restrict__ p1, const float* __restrict__ q1,
    ushort* __restrict__ Swt, ushort* __restrict__ Lwt, ushort* __restrict__ nWt,
    ushort* __restrict__ p0t, ushort* __restrict__ q0t,
    ushort* __restrict__ p1t, ushort* __restrict__ q1t) {
    const float* in; ushort* out; int K, N, Kp, Np;
    switch (blockIdx.z) {
        case 0: in = S_w; out = Swt; K = 128; N = 128; Kp = 128; Np = 128; break;
        case 1: in = L_w; out = Lwt; K = 128; N = 128; Kp = 128; Np = 128; break;
        case 2: in = n_w; out = nWt; K = 128; N = 128; Kp = 128; Np = 128; break;
        case 3: in = p0;  out = p0t; K = 128; N = HIDD; Kp = 128; Np = NPAD200; break;
        case 4: in = q0;  out = q0t; K = 128; N = HIDD; Kp = 128; Np = NPAD200; break;
        case 5: in = p1;  out = p1t; K = HIDD; N = HIDD; Kp = KPAD200; Np = NPAD200; break;
        default: in = q1; out = q1t; K = HIDD; N = HIDD; Kp = KPAD200; Np = NPAD200; break;
    }
    __shared__ float t[32][33];
    int k0 = blockIdx.x * 32, n0 = blockIdx.y * 32;
    if (k0 >= Kp || n0 >= Np) return;
    int tx = threadIdx.x & 31, ty = threadIdx.x >> 5;
    for (int i = ty; i < 32; i += 8) {
        int k = k0 + i, n = n0 + tx;
        t[i][tx] = (k < K && n < N) ? in[(size_t)k * N + n] : 0.f;
    }
    __syncthreads();
    for (int i = ty; i < 32; i += 8) {
        int n = n0 + i, k = k0 + tx;
        if (n < Np && k < Kp) out[(size_t)n * Kp + k] = f2b(t[tx][i]);
    }
}

// ================= MFMA bf16 GEMM (generic: projections & fc) =================
template <int WM, int WN, int OUTBF, int FUSE2>
__global__ __launch_bounds__(256) void k_mgemm(
    const ushort* __restrict__ A, int lda,
    const ushort* __restrict__ Bt, int ldb,
    const float* __restrict__ bias, void* __restrict__ Cout, int ldc,
    int M, int N, int K, int kChunk, int epi, int iofs, int npad,
    const ushort* __restrict__ A2, const ushort* __restrict__ Bt2,
    const float* __restrict__ bias2, void* __restrict__ Cout2, int iofs2) {
    if (FUSE2 && blockIdx.z == 1) { A = A2; Bt = Bt2; bias = bias2; Cout = Cout2; iofs = iofs2; }
    const int w = threadIdx.x >> 6, lane = threadIdx.x & 63;
    const int wr = w / WN, wc = w % WN;
    const int row0 = blockIdx.x * (WM * 64) + wr * 64;
    const int col0 = blockIdx.y * (WN * 64) + wc * 64;
    const int lr = lane & 15;
    const int kg = (lane >> 4) * 8;
    const int kb = FUSE2 ? 0 : blockIdx.z * kChunk;
    const int ke = kb + kChunk;

    f32x4 acc[4][4];
#pragma unroll
    for (int i = 0; i < 4; i++)
#pragma unroll
        for (int j = 0; j < 4; j++) acc[i][j] = (f32x4){0.f, 0.f, 0.f, 0.f};

    for (int kk = kb; kk < ke; kk += 32) {
        bf16x8 af[4], bfr[4];
#pragma unroll
        for (int i = 0; i < 4; i++) {
            int r = row0 + i * 16 + lr;
            r = min(r, M - 1);
            af[i] = *(const bf16x8*)(A + (size_t)r * lda + kk + kg);
        }
#pragma unroll
        for (int j = 0; j < 4; j++) {
            int c = col0 + j * 16 + lr;
            bfr[j] = *(const bf16x8*)(Bt + (size_t)c * ldb + kk + kg);
        }
#pragma unroll
        for (int i = 0; i < 4; i++)
#pragma unroll
            for (int j = 0; j < 4; j++)
                acc[i][j] = __builtin_amdgcn_mfma_f32_16x16x32_bf16(af[i], bfr[j], acc[i][j], 0, 0, 0);
    }

    const int cr = (lane >> 4) * 4, cc = lane & 15;
    if (!FUSE2 && gridDim.z > 1) {
        float* P = (float*)Cout + (size_t)blockIdx.z * M * ldc;
#pragma unroll
        for (int i = 0; i < 4; i++)
#pragma unroll
            for (int j = 0; j < 4; j++) {
                int col = col0 + j * 16 + cc;
                if (col >= N) continue;
#pragma unroll
                for (int t = 0; t < 4; t++) {
                    int row = row0 + i * 16 + cr + t;
                    if (row < M) P[(size_t)row * ldc + col] = acc[i][j][t];
                }
            }
    } else {
#pragma unroll
        for (int i = 0; i < 4; i++)
#pragma unroll
            for (int j = 0; j < 4; j++) {
                int col = col0 + j * 16 + cc;
                if (col >= (OUTBF ? npad : N)) continue;
                bool valid = col < N;
                float bi = (bias && valid) ? bias[col] : 0.f;
#pragma unroll
                for (int t = 0; t < 4; t++) {
                    int row = row0 + i * 16 + cr + t;
                    if (row >= M) continue;
                    float v = acc[i][j][t] + bi;
                    if (epi == 1) v = fmaxf(v, 0.f);
                    else if (epi == 2) v = ftanh(v);
                    else if (epi == 3) v = fsigmoid(v);
                    if (!valid) v = 0.f;
                    if (OUTBF) {
                        size_t idx = (iofs < 0) ? ((size_t)row * ldc + col)
                                   : ((size_t)row * ldc + ((size_t)(col >> 1) << 2) + (col & 1) + iofs);
                        ((ushort*)Cout)[idx] = f2b(v);
                    } else {
                        ((float*)Cout)[(size_t)row * ldc + col] = v;
                    }
                }
            }
    }
}

// ==== fused pair: c1=tanh(neigh1@W), c2=tanh(neigh2@W), entout=ent+c1+c2 ====
__global__ __launch_bounds__(256) void k_tanh2ent(
    const ushort* __restrict__ neigh1, const ushort* __restrict__ neigh2,
    const ushort* __restrict__ nWt, const float* __restrict__ ent,
    ushort* __restrict__ c1o, ushort* __restrict__ c2o, ushort* __restrict__ eo) {
    const int w = threadIdx.x >> 6, lane = threadIdx.x & 63;
    const int wr = w >> 1, wc = w & 1;
    const int row0 = blockIdx.x * 128 + wr * 64;
    const int col0 = wc * 64;
    const int lr = lane & 15, kg = (lane >> 4) * 8;

    f32x4 a1[4][4], a2[4][4];
#pragma unroll
    for (int i = 0; i < 4; i++)
#pragma unroll
        for (int j = 0; j < 4; j++) { a1[i][j] = (f32x4){0,0,0,0}; a2[i][j] = (f32x4){0,0,0,0}; }

    for (int kk = 0; kk < HD; kk += 32) {
        bf16x8 f1[4], f2v[4], bfr[4];
#pragma unroll
        for (int i = 0; i < 4; i++) {
            int r = min(row0 + i * 16 + lr, N_ENTS - 1);
            f1[i]  = *(const bf16x8*)(neigh1 + (size_t)r * HD + kk + kg);
            f2v[i] = *(const bf16x8*)(neigh2 + (size_t)r * HD + kk + kg);
        }
#pragma unroll
        for (int j = 0; j < 4; j++)
            bfr[j] = *(const bf16x8*)(nWt + (size_t)(col0 + j * 16 + lr) * HD + kk + kg);
#pragma unroll
        for (int i = 0; i < 4; i++)
#pragma unroll
            for (int j = 0; j < 4; j++) {
                a1[i][j] = __builtin_amdgcn_mfma_f32_16x16x32_bf16(f1[i],  bfr[j], a1[i][j], 0, 0, 0);
                a2[i][j] = __builtin_amdgcn_mfma_f32_16x16x32_bf16(f2v[i], bfr[j], a2[i][j], 0, 0, 0);
            }
    }

    const int cr = (lane >> 4) * 4, cc = lane & 15;
#pragma unroll
    for (int i = 0; i < 4; i++)
#pragma unroll
        for (int j = 0; j < 4; j++) {
            int col = col0 + j * 16 + cc;
#pragma unroll
            for (int t = 0; t < 4; t++) {
                int row = row0 + i * 16 + cr + t;
                if (row >= N_ENTS) continue;
                float t1 = ftanh(a1[i][j][t]);
                float t2 = ftanh(a2[i][j][t]);
                size_t idx = (size_t)row * HD + col;
                c1o[idx] = f2b(t1);
                c2o[idx] = f2b(t2);
                eo[idx] = f2b(ent[idx] + t1 + t2);
            }
        }
}

// ================= score GEMM: XCD-swizzled, LDS-staged NT f32x4 stores ======
__global__ __launch_bounds__(256) void k_score(
    const ushort* __restrict__ A, const ushort* __restrict__ Bt,
    const float* __restrict__ bias, float* __restrict__ C, int N) {
    __shared__ __align__(16) float st[4][16][68];
    const int w = threadIdx.x >> 6, lane = threadIdx.x & 63;
    const int lr = lane & 15, kg = (lane >> 4) * 8;
    const int cr = (lane >> 4) * 4, cc = lane & 15;
    int flat = blockIdx.y * 16 + blockIdx.x;
    int swz = (flat & 7) * 392 + (flat >> 3);         // 3136 = 8 * 392
    const int row0 = (swz & 15) * 64;
    const int colw = (swz >> 4) * 256 + w * 64;

    f32x4 acc[4][4];
#pragma unroll
    for (int i = 0; i < 4; i++)
#pragma unroll
        for (int j = 0; j < 4; j++) acc[i][j] = (f32x4){0.f, 0.f, 0.f, 0.f};

    for (int kk = 0; kk < HD; kk += 32) {
        bf16x8 af[4], bfr[4];
#pragma unroll
        for (int i = 0; i < 4; i++)
            af[i] = *(const bf16x8*)(A + (size_t)(row0 + i * 16 + lr) * HD + kk + kg);
#pragma unroll
        for (int j = 0; j < 4; j++)
            bfr[j] = *(const bf16x8*)(Bt + (size_t)(colw + j * 16 + lr) * HD + kk + kg);
#pragma unroll
        for (int i = 0; i < 4; i++)
#pragma unroll
            for (int j = 0; j < 4; j++)
                acc[i][j] = __builtin_amdgcn_mfma_f32_16x16x32_bf16(af[i], bfr[j], acc[i][j], 0, 0, 0);
    }

#pragma unroll
    for (int i = 0; i < 4; i++) {
#pragma unroll
        for (int j = 0; j < 4; j++) {
            int col = colw + j * 16 + cc;
            float bi = (col < N) ? bias[col] : 0.f;
#pragma unroll
            for (int t = 0; t < 4; t++)
                st[w][cr + t][j * 16 + cc] = fsigmoid(acc[i][j][t] + bi);
        }
#pragma unroll
        for (int p = 0; p < 4; p++) {
            int r = p * 4 + (lane >> 4);
            int cq = (lane & 15) * 4;
            f32x4 v = *(const f32x4*)&st[w][r][cq];
            int gc = colw + cq;
            if (gc < N)
                __builtin_nontemporal_store(v, (f32x4*)&C[(size_t)(row0 + i * 16 + r) * N + gc]);
        }
    }
}

// ================= fused 3-layer MLP (both MLPs via z switch) =================
__global__ __launch_bounds__(256) void k_mlp2(
    const ushort* __restrict__ A0, const ushort* __restrict__ W0t0,
    const float* __restrict__ b00, const ushort* __restrict__ W1t0,
    const float* __restrict__ b10, const float* __restrict__ w20,
    const float* __restrict__ b20, float* __restrict__ xo0,
    const ushort* __restrict__ A1, const ushort* __restrict__ W0t1,
    const float* __restrict__ b01, const ushort* __restrict__ W1t1,
    const float* __restrict__ b11, const float* __restrict__ w21,
    const float* __restrict__ b21, float* __restrict__ xo1) {
    const ushort* A   = blockIdx.z ? A1 : A0;
    const ushort* W0t = blockIdx.z ? W0t1 : W0t0;
    const float*  b0  = blockIdx.z ? b01 : b00;
    const ushort* W1t = blockIdx.z ? W1t1 : W1t0;
    const float*  b1  = blockIdx.z ? b11 : b10;
    const float*  w2  = blockIdx.z ? w21 : w20;
    const float*  b2  = blockIdx.z ? b21 : b20;
    float*        x   = blockIdx.z ? xo1 : xo0;

    __shared__ __align__(16) char lbuf[64 * 232 * 2];
    __shared__ float w2e[256], b1e[256], b0e[256];
    const int tid = threadIdx.x;
    const int w = tid >> 6, lane = tid & 63;
    const int lr = lane & 15, kg = (lane >> 4) * 8;
    const int cr = (lane >> 4) * 4, cc = lane & 15;
    const int row0 = blockIdx.x * 64;
    {
        int c = tid;
        w2e[c] = (c < HIDD) ? w2[c] : 0.f;
        b1e[c] = (c < HIDD) ? b1[c] : 0.f;
        b0e[c] = (c < HIDD) ? b0[c] : 0.f;
    }
    __syncthreads();
    ushort* g1 = (ushort*)lbuf;

    f32x4 acc[4][4];
#pragma unroll
    for (int i = 0; i < 4; i++)
#pragma unroll
        for (int j = 0; j < 4; j++) acc[i][j] = (f32x4){0.f, 0.f, 0.f, 0.f};
    for (int kk = 0; kk < 128; kk += 32) {
        bf16x8 af[4], bfr[4];
#pragma unroll
        for (int i = 0; i < 4; i++)
            af[i] = *(const bf16x8*)(A + (size_t)(row0 + i * 16 + lr) * HD + kk + kg);
#pragma unroll
        for (int j = 0; j < 4; j++)
            bfr[j] = *(const bf16x8*)(W0t + (size_t)(w * 64 + j * 16 + lr) * 128 + kk + kg);
#pragma unroll
        for (int i = 0; i < 4; i++)
#pragma unroll
            for (int j = 0; j < 4; j++)
                acc[i][j] = __builtin_amdgcn_mfma_f32_16x16x32_bf16(af[i], bfr[j], acc[i][j], 0, 0, 0);
    }
#pragma unroll
    for (int i = 0; i < 4; i++)
#pragma unroll
        for (int j = 0; j < 4; j++) {
            int col = w * 64 + j * 16 + cc;
            if (col < KPAD200) {
                float bi = b0e[col];
#pragma unroll
                for (int t = 0; t < 4; t++)
                    g1[(i * 16 + cr + t) * 232 + col] = f2b(fmaxf(acc[i][j][t] + bi, 0.f));
            }
        }
    __syncthreads();

    f32x4 a2[4][4];
#pragma unroll
    for (int i = 0; i < 4; i++)
#pragma unroll
        for (int j = 0; j < 4; j++) a2[i][j] = (f32x4){0.f, 0.f, 0.f, 0.f};
    for (int ks = 0; ks < 7; ks++) {
        int kk = ks * 32;
        bf16x8 af[4], bfr[4];
#pragma unroll
        for (int i = 0; i < 4; i++)
            af[i] = *(const bf16x8*)(g1 + (i * 16 + lr) * 232 + kk + kg);
#pragma unroll
        for (int j = 0; j < 4; j++)
            bfr[j] = *(const bf16x8*)(W1t + (size_t)(w * 64 + j * 16 + lr) * KPAD200 + kk + kg);
#pragma unroll
        for (int i = 0; i < 4; i++)
#pragma unroll
            for (int j = 0; j < 4; j++)
                a2[i][j] = __builtin_amdgcn_mfma_f32_16x16x32_bf16(af[i], bfr[j], a2[i][j], 0, 0, 0);
    }
    __syncthreads();

    float* pbuf = (float*)lbuf;   // [64][65]
#pragma unroll
    for (int i = 0; i < 4; i++)
#pragma unroll
        for (int t = 0; t < 4; t++) {
            float s = 0.f;
#pragma unroll
            for (int j = 0; j < 4; j++) {
                int col = w * 64 + j * 16 + cc;
                s += fmaxf(a2[i][j][t] + b1e[col], 0.f) * w2e[col];
            }
            pbuf[(i * 16 + cr + t) * 65 + w * 16 + cc] = s;
        }
    __syncthreads();
    if (tid < 64) {
        float s = b2[0];
        for (int q = 0; q < 64; q++) s += pbuf[tid * 65 + q];
        int gr = row0 + tid;
        if (gr < N_ENTS) x[gr] = s;
    }
}

// ================= CSR build =================
__global__ void k_deg(const int* __restrict__ dst, int* __restrict__ deg) {
    int e = blockIdx.x * 256 + threadIdx.x;
    if (e < E_EDGES) atomicAdd(&deg[dst[e]], 1);
}

__global__ void k_scan1(const int* __restrict__ in, int* __restrict__ out,
                        int* __restrict__ bsum, int n) {
    __shared__ int sh[256];
    int i = blockIdx.x * 256 + threadIdx.x;
    int v = (i < n) ? in[i] : 0;
    sh[threadIdx.x] = v; __syncthreads();
    for (int off = 1; off < 256; off <<= 1) {
        int t = (threadIdx.x >= off) ? sh[threadIdx.x - off] : 0;
        __syncthreads();
        sh[threadIdx.x] += t;
        __syncthreads();
    }
    if (i < n) out[i] = sh[threadIdx.x] - v;
    if (threadIdx.x == 255) bsum[blockIdx.x] = sh[255];
}

__global__ void k_scan2(int* __restrict__ bsum, int nb) {
    __shared__ int sh[1024];
    int t = threadIdx.x;
    int v = (t < nb) ? bsum[t] : 0;
    sh[t] = v; __syncthreads();
    for (int off = 1; off < 1024; off <<= 1) {
        int u = (t >= off) ? sh[t - off] : 0;
        __syncthreads();
        sh[t] += u;
        __syncthreads();
    }
    if (t < nb) bsum[t] = sh[t] - v;
}

__global__ void k_scan3(int* __restrict__ out, const int* __restrict__ bsum, int n) {
    int i = blockIdx.x * 256 + threadIdx.x;
    if (i < n) out[i] += bsum[blockIdx.x];
}

// fused scatter: writes sidx directly
__global__ void k_scatter2(const int* __restrict__ src, const int* __restrict__ dst,
                           const int* __restrict__ rel_id, const int* __restrict__ start,
                           int* __restrict__ cursor, int4* __restrict__ sidx) {
    int e = blockIdx.x * 256 + threadIdx.x;
    if (e < E_EDGES) {
        int n = dst[e];
        int p = start[n] + atomicAdd(&cursor[n], 1);
        sidx[p] = make_int4(src[e], n, rel_id[e], e);
    }
}

// ====== FUSED edge pipeline: scores + softmax/top-15 + weighted agg per node ======
// Block per node (4 waves). Phase A: gather src/rel rows, per-edge score via
// 64-lane reduce (dst row from LDS, loaded once). Phase B: softmax + rank in LDS.
// Phase C: weighted sum, re-gathering rows (L1/L2-hot from phase A).
__global__ __launch_bounds__(256) void k_edge(
    const int4* __restrict__ sidx, const int* __restrict__ start, const int* __restrict__ deg,
    const ushort* __restrict__ ep, const ushort* __restrict__ rel,
    ushort* __restrict__ neigh1, ushort* __restrict__ neigh2) {
    __shared__ ushort dstrow[256];
    __shared__ float2 s_sc[SCAP];
    __shared__ float2 s_w[SCAP];
    __shared__ int    s_ei[SCAP];
    __shared__ float2 redm[4], redz[4];
    __shared__ float4 part[3][64];
    const int n = blockIdx.x, tid = threadIdx.x;
    const int wid = tid >> 6, g = tid & 63;
    const int b = start[n];
    const int d = min(deg[n], SCAP);    // input max degree ~45 << SCAP
    if (d == 0) {
        if (tid < 64) {
            ((uint*)(neigh1 + (size_t)n * HD))[g] = 0u;
            ((uint*)(neigh2 + (size_t)n * HD))[g] = 0u;
        }
        return;
    }
    if (tid < 128) ((uint*)dstrow)[tid] = ((const uint*)(ep + (size_t)n * 256))[tid];
    __syncthreads();

    // ---- phase A: per-edge scores (wave per edge, wave-strided) ----
    u16x4 dq = *(const u16x4*)(dstrow + g * 4);
    const float d0 = b2f(dq[0]), d1 = b2f(dq[1]), d2 = b2f(dq[2]), d3 = b2f(dq[3]);
    for (int i = wid; i < d; i += 4) {
        int4 si = sidx[b + i];
        u16x4 v = *(const u16x4*)(ep + (size_t)si.x * 256 + g * 4);
        uint  r = *(const uint*)(rel + (size_t)si.z * 128 + g * 2);
        float rx = b2f((ushort)(r & 0xffffu)), ry = b2f((ushort)(r >> 16));
        float a = b2f(v[0]) * rx * d0 + b2f(v[1]) * ry * d1;
        float bs = b2f(v[2]) * rx * d2 + b2f(v[3]) * ry * d3;
#pragma unroll
        for (int m = 32; m; m >>= 1) { a += __shfl_xor(a, m, 64); bs += __shfl_xor(bs, m, 64); }
        if (g == 0) { s_sc[i] = make_float2(a, bs); s_ei[i] = si.w; }
    }
    __syncthreads();

    // ---- phase B: softmax + top-15 ----
    float m1 = -INFINITY, m2 = -INFINITY;
    for (int i = tid; i < d; i += 256) {
        float2 s = s_sc[i];
        m1 = fmaxf(m1, s.x); m2 = fmaxf(m2, s.y);
    }
#pragma unroll
    for (int m = 32; m; m >>= 1) { m1 = fmaxf(m1, __shfl_xor(m1, m, 64)); m2 = fmaxf(m2, __shfl_xor(m2, m, 64)); }
    if (g == 0) redm[wid] = make_float2(m1, m2);
    __syncthreads();
    m1 = fmaxf(fmaxf(redm[0].x, redm[1].x), fmaxf(redm[2].x, redm[3].x));
    m2 = fmaxf(fmaxf(redm[0].y, redm[1].y), fmaxf(redm[2].y, redm[3].y));
    float z1 = 0.f, z2 = 0.f;
    for (int i = tid; i < d; i += 256) {
        float2 s = s_sc[i];
        z1 += fexp2((s.x - m1) * L2E); z2 += fexp2((s.y - m2) * L2E);
    }
#pragma unroll
    for (int m = 32; m; m >>= 1) { z1 += __shfl_xor(z1, m, 64); z2 += __shfl_xor(z2, m, 64); }
    if (g == 0) redz[wid] = make_float2(z1, z2);
    __syncthreads();
    z1 = redz[0].x + redz[1].x + redz[2].x + redz[3].x;
    z2 = redz[0].y + redz[1].y + redz[2].y + redz[3].y;
    const float iz1 = frcp(z1), iz2 = frcp(z2);
    if (d <= TOPK_K) {
        for (int i = tid; i < d; i += 256) {
            float2 s = s_sc[i];
            s_w[i] = make_float2(fexp2((s.x - m1) * L2E) * iz1,
                                 fexp2((s.y - m2) * L2E) * iz2);
        }
    } else {
        for (int i = tid; i < d; i += 256) {
            float2 sp = s_sc[i];
            int ei = s_ei[i];
            int r1 = 0, r2 = 0;
            for (int j = 0; j < d; j++) {
                float2 sq = s_sc[j];
                int ej = s_ei[j];
                r1 += (sq.x > sp.x) || (sq.x == sp.x && ej < ei);
                r2 += (sq.y > sp.y) || (sq.y == sp.y && ej < ei);
            }
            s_w[i] = make_float2(r1 < TOPK_K ? fexp2((sp.x - m1) * L2E) * iz1 : 0.f,
                                 r2 < TOPK_K ? fexp2((sp.y - m2) * L2E) * iz2 : 0.f);
        }
    }
    __syncthreads();

    // ---- phase C: weighted aggregation (2 chains/wave, cache-hot gathers) ----
    float2 a1 = {0.f, 0.f}, a2 = {0.f, 0.f}, c1 = {0.f, 0.f}, c2 = {0.f, 0.f};
    for (int i = wid; i < d; i += 8) {
        int iB = i + 4;
        bool hB = iB < d;
        int4 siA = sidx[b + i];
        int4 siB = hB ? sidx[b + iB] : siA;
        float2 wA = s_w[i];
        float2 wB = hB ? s_w[iB] : make_float2(0.f, 0.f);
        u16x4 vA = *(const u16x4*)(ep + (size_t)siA.x * 256 + g * 4);
        uint  rA = *(const uint*)(rel + (size_t)siA.z * 128 + g * 2);
        u16x4 vB = *(const u16x4*)(ep + (size_t)siB.x * 256 + g * 4);
        uint  rB = *(const uint*)(rel + (size_t)siB.z * 128 + g * 2);
        float rx = b2f((ushort)(rA & 0xffffu)), ry = b2f((ushort)(rA >> 16));
        a1.x += wA.x * b2f(vA[0]) * rx;  a1.y += wA.x * b2f(vA[1]) * ry;
        a2.x += wA.y * b2f(vA[2]) * rx;  a2.y += wA.y * b2f(vA[3]) * ry;
        rx = b2f((ushort)(rB & 0xffffu)); ry = b2f((ushort)(rB >> 16));
        c1.x += wB.x * b2f(vB[0]) * rx;  c1.y += wB.x * b2f(vB[1]) * ry;
        c2.x += wB.y * b2f(vB[2]) * rx;  c2.y += wB.y * b2f(vB[3]) * ry;
    }
    a1.x += c1.x; a1.y += c1.y; a2.x += c2.x; a2.y += c2.y;
    if (wid > 0) part[wid - 1][g] = make_float4(a1.x, a1.y, a2.x, a2.y);
    __syncthreads();
    if (wid == 0) {
#pragma unroll
        for (int k = 0; k < 3; k++) {
            float4 p = part[k][g];
            a1.x += p.x; a1.y += p.y; a2.x += p.z; a2.y += p.w;
        }
        uint o1 = (uint)f2b(a1.x) | ((uint)f2b(a1.y) << 16);
        uint o2 = (uint)f2b(a2.x) | ((uint)f2b(a2.y) << 16);
        ((uint*)(neigh1 + (size_t)n * HD))[g] = o1;
        ((uint*)(neigh2 + (size_t)n * HD))[g] = o2;
    }
}

// ================= corr (merged, one block) =================
__global__ void k_corr(const float* __restrict__ x1, const float* __restrict__ x2,
                       float* __restrict__ out) {
    __shared__ float sa[1024], sb[1024], sc_[1024];
    int t = threadIdx.x;
    float s1 = 0.f, s2 = 0.f;
    for (int i = t; i < N_ENTS; i += 1024) { s1 += x1[i]; s2 += x2[i]; }
    sa[t] = s1; sb[t] = s2; __syncthreads();
    for (int o = 512; o > 0; o >>= 1) {
        if (t < o) { sa[t] += sa[t + o]; sb[t] += sb[t + o]; }
        __syncthreads();
    }
    float m1 = sa[0] / (float)N_ENTS, m2 = sb[0] / (float)N_ENTS;
    __syncthreads();
    float a11 = 0.f, a22 = 0.f, a12 = 0.f;
    for (int i = t; i < N_ENTS; i += 1024) {
        float a = x1[i] - m1, b = x2[i] - m2;
        a11 += a * a; a22 += b * b; a12 += a * b;
    }
    sa[t] = a11; sb[t] = a22; sc_[t] = a12; __syncthreads();
    for (int o = 512; o > 0; o >>= 1) {
        if (t < o) { sa[t] += sa[t + o]; sb[t] += sb[t + o]; sc_[t] += sc_[t + o]; }
        __syncthreads();
    }
    if (t == 0) {
        float v11 = sa[0] / (float)N_ENTS, v22 = sb[0] / (float)N_ENTS, v12 = sc_[0] / (float)N_ENTS;
        out[0] = fabsf(v12) / (sqrtf(v11) * sqrtf(v22));
    }
}

// ====== ConvE conv: fixed-channel threads, filter in regs, LDS out staging ======
__global__ __launch_bounds__(192) void k_conv(
    const int* __restrict__ h_id, const int* __restrict__ r_id,
    const ushort* __restrict__ entout, const ushort* __restrict__ prel,
    const float* __restrict__ cw, const float* __restrict__ cb,
    ushort* __restrict__ out) {
    __shared__ float img[256];
    __shared__ ushort lout[FLATD];      // 19.2 KB
    int b = blockIdx.x, tid = threadIdx.x;
    for (int i = tid; i < 256; i += 192) {
        img[i] = (i < 128) ? b2f(entout[(size_t)h_id[b] * HD + i])
                           : b2f(prel[(size_t)r_id[b] * HD + (i - 128)]);
    }
    const int o = tid >> 1, jp = tid & 1;   // channel 0..95, j-half 0..1
    float f[49];
#pragma unroll
    for (int k = 0; k < 49; k++) f[k] = cw[o * 49 + k];
    const float bi = cb[o];
    __syncthreads();
    for (int i = 0; i < 10; i++) {
#pragma unroll
        for (int jj = 0; jj < 5; jj++) {
            int j = jp * 5 + jj;
            float acc = bi;
#pragma unroll
            for (int ki = 0; ki < 7; ki++)
#pragma unroll
                for (int kj = 0; kj < 7; kj++)
                    acc += img[(i + ki) * 16 + (j + kj)] * f[ki * 7 + kj];
            lout[o * 100 + i * 10 + j] = f2b(fmaxf(acc, 0.f));
        }
    }
    __syncthreads();
    uint* go = (uint*)(out + (size_t)b * FLATD);
    const uint* lo = (const uint*)lout;
    for (int idx = tid; idx < FLATD / 2; idx += 192) go[idx] = lo[idx];
}

// ================= split-K reduce for fc =================
__global__ void k_fcreduce(const float* __restrict__ part, const float* __restrict__ bias,
                           ushort* __restrict__ out) {
    int i = blockIdx.x * 256 + threadIdx.x;
    if (i >= BSZ * HD) return;
    float s = 0.f;
    for (int z = 0; z < SPLITK; z++) s += part[(size_t)z * BSZ * HD + i];
    s += bias[i & (HD - 1)];
    out[i] = f2b(fmaxf(s, 0.f));
}

// ================= host launcher =================
extern "C" void kernel_launch(void* const* d_in, const int* in_sizes, int n_in,
                              void* d_out, int out_size, void* d_ws, size_t ws_size,
                              hipStream_t stream) {
    const int* h_id    = (const int*)d_in[0];
    const int* r_id    = (const int*)d_in[1];
    const int* src     = (const int*)d_in[2];
    const int* dst     = (const int*)d_in[3];
    const int* rel_id  = (const int*)d_in[4];
    const float* ent_emb  = (const float*)d_in[5];
    const float* rel_emb0 = (const float*)d_in[6];
    const float* neigh_w  = (const float*)d_in[7];
    const float* S_w = (const float*)d_in[8];
    const float* S_b = (const float*)d_in[9];
    const float* L_w = (const float*)d_in[10];
    const float* L_b = (const float*)d_in[11];
    const float* pred_rel = (const float*)d_in[12];
    const float* phi_w0 = (const float*)d_in[13]; const float* phi_b0 = (const float*)d_in[14];
    const float* phi_w1 = (const float*)d_in[15]; const float* phi_b1 = (const float*)d_in[16];
    const float* phi_w2 = (const float*)d_in[17]; const float* phi_b2 = (const float*)d_in[18];
    const float* psi_w0 = (const float*)d_in[19]; const float* psi_b0 = (const float*)d_in[20];
    const float* psi_w1 = (const float*)d_in[21]; const float* psi_b1 = (const float*)d_in[22];
    const float* psi_w2 = (const float*)d_in[23]; const float* psi_b2 = (const float*)d_in[24];
    const float* conv_w = (const float*)d_in[25]; const float* conv_b = (const float*)d_in[26];
    const float* fc_w   = (const float*)d_in[27]; const float* fc_b   = (const float*)d_in[28];
    const float* score_b= (const float*)d_in[29];

    char* base = (char*)d_ws;
    ushort* ep       = (ushort*)(base + OFF_EP);
    ushort* entout_bf= (ushort*)(base + OFF_ENTOUT);
    ushort* rel_bf   = (ushort*)(base + OFF_RELBF);
    ushort* prel_bf  = (ushort*)(base + OFF_PRELBF);
    ushort* Swt      = (ushort*)(base + OFF_SWT);
    ushort* Lwt      = (ushort*)(base + OFF_LWT);
    ushort* nWt      = (ushort*)(base + OFF_NWT);
    ushort* p0t      = (ushort*)(base + OFF_P0T);
    ushort* q0t      = (ushort*)(base + OFF_Q0T);
    ushort* p1t      = (ushort*)(base + OFF_P1T);
    ushort* q1t      = (ushort*)(base + OFF_Q1T);
    ushort* fct      = (ushort*)(base + OFF_FCT);
    int4*   sidx     = (int4*)(base + OFF_SIDX);
    int*    deg      = (int*)(base + OFF_DEG);
    int*    startp   = (int*)(base + OFF_START);
    int*    cursor   = (int*)(base + OFF_CUR);
    int*    bsum     = (int*)(base + OFF_BSUM);
    float*  x1       = (float*)(base + OFF_X1);
    float*  x2       = (float*)(base + OFF_X2);
    ushort* xfc_bf   = (ushort*)(base + OFF_XFC);
    ushort* c1_bf    = (ushort*)(base + OFF_EP);                 // alias (ep dead after edge)
    ushort* c2_bf    = (ushort*)(base + OFF_EP + 12812288);
    ushort* ent_bf   = (ushort*)(base + OFF_ARENA);              // temp: arena before neigh use
    ushort* neigh1_bf= (ushort*)(base + OFF_ARENA);
    ushort* neigh2_bf= (ushort*)(base + OFF_ARENA + 12812288);
    ushort* convout  = (ushort*)(base + OFF_ARENA);
    float*  fcpart   = (float*)(base + OFF_ARENA + 22421504);
    float*  outf     = (float*)d_out;

    // ---- phase 0: conversions & weight transposes (fused) ----
    k_cvt<<<dim3((MPAD * HD + 255) / 256), 256, 0, stream>>>(ent_emb, ent_bf, N_ENTS, MPAD, HD);
    k_cvt2<<<dim3(500, 1, 2), 256, 0, stream>>>(rel_emb0, rel_bf, pred_rel, prel_bf, 1000 * HD);
    k_tcvt7<<<dim3(7, 8, 7), 256, 0, stream>>>(S_w, L_w, neigh_w, phi_w0, psi_w0, phi_w1, psi_w1,
                                               Swt, Lwt, nWt, p0t, q0t, p1t, q1t);
    k_tcvtT<<<dim3(300, 4), 256, 0, stream>>>(fc_w, fct, FLATD, 128, FLATD, 128);

    // ---- phase 1: projections (fused pair) -> interleaved ep table ----
    k_mgemm<2,2,1,1><<<dim3(391, 1, 2), 256, 0, stream>>>(
        ent_bf, HD, Swt, HD, S_b, ep, 256, N_ENTS, HD, HD, HD, 0, 0, HD,
        ent_bf, Lwt, L_b, ep, 2);

    // ---- phase 2: CSR build ----
    hipMemsetAsync(deg, 0, N_ENTS * sizeof(int), stream);
    hipMemsetAsync(cursor, 0, N_ENTS * sizeof(int), stream);
    k_deg<<<dim3((E_EDGES + 255) / 256), 256, 0, stream>>>(dst, deg);
    int nscan = (N_ENTS + 255) / 256;
    k_scan1<<<dim3(nscan), 256, 0, stream>>>(deg, startp, bsum, N_ENTS);
    k_scan2<<<dim3(1), 1024, 0, stream>>>(bsum, nscan);
    k_scan3<<<dim3(nscan), 256, 0, stream>>>(startp, bsum, N_ENTS);
    k_scatter2<<<dim3((E_EDGES + 255) / 256), 256, 0, stream>>>(src, dst, rel_id, startp, cursor, sidx);

    // ---- phase 3-5: FUSED edge pipeline ----
    k_edge<<<dim3(N_ENTS), 256, 0, stream>>>(sidx, startp, deg, ep, rel_bf,
                                             neigh1_bf, neigh2_bf);

    // ---- phase 6+7: c1/c2 = tanh(neigh @ W) + ent_out, fused ----
    k_tanh2ent<<<dim3(391), 256, 0, stream>>>(neigh1_bf, neigh2_bf, nWt, ent_emb,
                                              c1_bf, c2_bf, entout_bf);

    // ---- phase 8: fused MLPs (both via z) ----
    k_mlp2<<<dim3(MPAD / 64, 1, 2), 256, 0, stream>>>(
        c1_bf, p0t, phi_b0, p1t, phi_b1, phi_w2, phi_b2, x1,
        c2_bf, q0t, psi_b0, q1t, psi_b1, psi_w2, psi_b2, x2);

    // ---- phase 9: corr (merged) ----
    k_corr<<<dim3(1), 1024, 0, stream>>>(x1, x2, outf + OUT_SCORE);

    // ---- phase 10-11: ConvE ----
    k_conv<<<dim3(BSZ), 192, 0, stream>>>(h_id, r_id, entout_bf, prel_bf, conv_w, conv_b, convout);
    k_mgemm<2,2,0,0><<<dim3(8, 1, SPLITK), 256, 0, stream>>>(
        convout, FLATD, fct, FLATD, nullptr, fcpart, HD, BSZ, HD, FLATD, FLATD / SPLITK, 0, -1, HD,
        nullptr, nullptr, nullptr, nullptr, 0);
    k_fcreduce<<<dim3((BSZ * HD + 255) / 256), 256, 0, stream>>>(fcpart, fc_b, xfc_bf);

    // ---- phase 12: score GEMM (XCD-swizzled, NT stores) ----
    k_score<<<dim3(16, 196), 256, 0, stream>>>(xfc_bf, entout_bf, score_b, outf, N_ENTS);
}

// Round 10
// 611.605 us; speedup vs baseline: 1.2433x; 1.2433x over previous
//
#include <hip/hip_runtime.h>
#include <math.h>

typedef unsigned short ushort;
typedef unsigned int   uint;
typedef short bf16x8 __attribute__((ext_vector_type(8)));
typedef float f32x4  __attribute__((ext_vector_type(4)));
typedef ushort u16x8 __attribute__((ext_vector_type(8)));
typedef ushort u16x4 __attribute__((ext_vector_type(4)));

// ---------------- problem constants ----------------
#define N_ENTS   50000
#define E_EDGES  800000
#define HD       128
#define BSZ      1024
#define C_CH     96
#define FLATD    9600
#define TOPK_K   15
#define HIDD     200
#define SPLITK   10
#define OUT_SCORE ((size_t)BSZ * N_ENTS)

#define MPAD     50048            // 391*128
#define NPAD_ENT 50176            // 196*256
#define KPAD200  224
#define NPAD200  256
#define L2E      1.4426950408889634f

// ---------------- workspace layout (byte offsets) ----------------
#define OFF_EP       ((size_t)0)            // ushort [50048][256] interleaved c/p (c1/c2 alias later)
#define OFF_ENTOUT   ((size_t)25624576)     // ushort [50176][128]
#define OFF_RELBF    ((size_t)38469632)     // ushort [1000][128]
#define OFF_PRELBF   ((size_t)38725632)
#define OFF_SWT      ((size_t)38981632)     // ushort [128][128]
#define OFF_LWT      ((size_t)39014400)
#define OFF_NWT      ((size_t)39047168)
#define OFF_P0T      ((size_t)39079936)     // ushort [256][128]
#define OFF_Q0T      ((size_t)39145472)
#define OFF_P1T      ((size_t)39211008)     // ushort [256][224]
#define OFF_Q1T      ((size_t)39325696)
#define OFF_FCT      ((size_t)39440384)     // ushort [128][9600]
#define OFF_SC       ((size_t)41897984)     // float2 [800000]
#define OFF_W        ((size_t)48297984)     // float2 [800000]
#define OFF_SIDX     ((size_t)54697984)     // int4 [800000]
#define OFF_DEG      ((size_t)70697984)     // int [50000]
#define OFF_START    ((size_t)70897984)
#define OFF_CUR      ((size_t)71097984)
#define OFF_BSUM     ((size_t)71297984)     // int [1024]
#define OFF_X1       ((size_t)71302080)     // float [50000]
#define OFF_X2       ((size_t)71502080)
#define OFF_XFC      ((size_t)71702336)     // ushort [1024][128]
#define OFF_ARENA    ((size_t)71964480)
// arena: ent_bf=+0 (u16[50048][128]) [dead after proj]
//        neigh1=+0, neigh2=+12812288 [dead after k_tanh2ent]
//        convout=+0 (u16[1024][9600]), fcpart=+22421504 (f32[10][1024][128])
// c1 = EP+0 (u16[50048][128]), c2 = EP+12812288  (EP dead after k_agg)

// ---------------- helpers ----------------
__device__ inline ushort f2b(float f) {
    uint u = __float_as_uint(f);
    return (ushort)((u + 0x7fffu + ((u >> 16) & 1u)) >> 16);  // RNE
}
__device__ inline float b2f(ushort u) { return __uint_as_float((uint)u << 16); }
__device__ inline float fexp2(float x) { return __builtin_amdgcn_exp2f(x); }
__device__ inline float frcp(float x)  { return __builtin_amdgcn_rcpf(x); }
__device__ inline float fsigmoid(float x) { return frcp(1.f + fexp2(-x * L2E)); }
__device__ inline float ftanh(float x) {
    float ax = fabsf(x);
    float t = fexp2(ax * (-2.f * L2E));
    float r = (1.f - t) * frcp(1.f + t);
    return copysignf(r, x);
}

// ---------------- conversion kernels ----------------
__global__ void k_cvt(const float* __restrict__ in, ushort* __restrict__ out,
                      int M, int Mpad, int K) {
    int i = blockIdx.x * 256 + threadIdx.x;
    if (i >= Mpad * K) return;
    int r = i / K;
    out[i] = (r < M) ? f2b(in[i]) : (ushort)0;
}

__global__ void k_cvt2(const float* __restrict__ in0, ushort* __restrict__ out0,
                       const float* __restrict__ in1, ushort* __restrict__ out1, int n) {
    const float* in = blockIdx.z ? in1 : in0;
    ushort* out = blockIdx.z ? out1 : out0;
    int i = blockIdx.x * 256 + threadIdx.x;
    if (i < n) out[i] = f2b(in[i]);
}

__global__ __launch_bounds__(256) void k_tcvtT(const float* __restrict__ in, ushort* __restrict__ out,
                                               int K, int N, int Kpad, int Npad) {
    __shared__ float t[32][33];
    int k0 = blockIdx.x * 32, n0 = blockIdx.y * 32;
    int tx = threadIdx.x & 31, ty = threadIdx.x >> 5;
    for (int i = ty; i < 32; i += 8) {
        int k = k0 + i, n = n0 + tx;
        t[i][tx] = (k < K && n < N) ? in[(size_t)k * N + n] : 0.f;
    }
    __syncthreads();
    for (int i = ty; i < 32; i += 8) {
        int n = n0 + i, k = k0 + tx;
        if (n < Npad && k < Kpad) out[(size_t)n * Kpad + k] = f2b(t[tx][i]);
    }
}

__global__ __launch_bounds__(256) void k_tcvt7(
    const float* __restrict__ S_w, const float* __restrict__ L_w, const float* __restrict__ n_w,
    const float* __restrict__ p0, const float* __restrict__ q0,
    const float* __restrict__ p1, const float* __restrict__ q1,
    ushort* __restrict__ Swt, ushort* __restrict__ Lwt, ushort* __restrict__ nWt,
    ushort* __restrict__ p0t, ushort* __restrict__ q0t,
    ushort* __restrict__ p1t, ushort* __restrict__ q1t) {
    const float* in; ushort* out; int K, N, Kp, Np;
    switch (blockIdx.z) {
        case 0: in = S_w; out = Swt; K = 128; N = 128; Kp = 128; Np = 128; break;
        case 1: in = L_w; out = Lwt; K = 128; N = 128; Kp = 128; Np = 128; break;
        case 2: in = n_w; out = nWt; K = 128; N = 128; Kp = 128; Np = 128; break;
        case 3: in = p0;  out = p0t; K = 128; N = HIDD; Kp = 128; Np = NPAD200; break;
        case 4: in = q0;  out = q0t; K = 128; N = HIDD; Kp = 128; Np = NPAD200; break;
        case 5: in = p1;  out = p1t; K = HIDD; N = HIDD; Kp = KPAD200; Np = NPAD200; break;
        default: in = q1; out = q1t; K = HIDD; N = HIDD; Kp = KPAD200; Np = NPAD200; break;
    }
    __shared__ float t[32][33];
    int k0 = blockIdx.x * 32, n0 = blockIdx.y * 32;
    if (k0 >= Kp || n0 >= Np) return;
    int tx = threadIdx.x & 31, ty = threadIdx.x >> 5;
    for (int i = ty; i < 32; i += 8) {
        int k = k0 + i, n = n0 + tx;
        t[i][tx] = (k < K && n < N) ? in[(size_t)k * N + n] : 0.f;
    }
    __syncthreads();
    for (int i = ty; i < 32; i += 8) {
        int n = n0 + i, k = k0 + tx;
        if (n < Np && k < Kp) out[(size_t)n * Kp + k] = f2b(t[tx][i]);
    }
}

// ================= MFMA bf16 GEMM (generic: projections & fc) =================
template <int WM, int WN, int OUTBF, int FUSE2>
__global__ __launch_bounds__(256) void k_mgemm(
    const ushort* __restrict__ A, int lda,
    const ushort* __restrict__ Bt, int ldb,
    const float* __restrict__ bias, void* __restrict__ Cout, int ldc,
    int M, int N, int K, int kChunk, int epi, int iofs, int npad,
    const ushort* __restrict__ A2, const ushort* __restrict__ Bt2,
    const float* __restrict__ bias2, void* __restrict__ Cout2, int iofs2) {
    if (FUSE2 && blockIdx.z == 1) { A = A2; Bt = Bt2; bias = bias2; Cout = Cout2; iofs = iofs2; }
    const int w = threadIdx.x >> 6, lane = threadIdx.x & 63;
    const int wr = w / WN, wc = w % WN;
    const int row0 = blockIdx.x * (WM * 64) + wr * 64;
    const int col0 = blockIdx.y * (WN * 64) + wc * 64;
    const int lr = lane & 15;
    const int kg = (lane >> 4) * 8;
    const int kb = FUSE2 ? 0 : blockIdx.z * kChunk;
    const int ke = kb + kChunk;

    f32x4 acc[4][4];
#pragma unroll
    for (int i = 0; i < 4; i++)
#pragma unroll
        for (int j = 0; j < 4; j++) acc[i][j] = (f32x4){0.f, 0.f, 0.f, 0.f};

    for (int kk = kb; kk < ke; kk += 32) {
        bf16x8 af[4], bfr[4];
#pragma unroll
        for (int i = 0; i < 4; i++) {
            int r = row0 + i * 16 + lr;
            r = min(r, M - 1);
            af[i] = *(const bf16x8*)(A + (size_t)r * lda + kk + kg);
        }
#pragma unroll
        for (int j = 0; j < 4; j++) {
            int c = col0 + j * 16 + lr;
            bfr[j] = *(const bf16x8*)(Bt + (size_t)c * ldb + kk + kg);
        }
#pragma unroll
        for (int i = 0; i < 4; i++)
#pragma unroll
            for (int j = 0; j < 4; j++)
                acc[i][j] = __builtin_amdgcn_mfma_f32_16x16x32_bf16(af[i], bfr[j], acc[i][j], 0, 0, 0);
    }

    const int cr = (lane >> 4) * 4, cc = lane & 15;
    if (!FUSE2 && gridDim.z > 1) {
        float* P = (float*)Cout + (size_t)blockIdx.z * M * ldc;
#pragma unroll
        for (int i = 0; i < 4; i++)
#pragma unroll
            for (int j = 0; j < 4; j++) {
                int col = col0 + j * 16 + cc;
                if (col >= N) continue;
#pragma unroll
                for (int t = 0; t < 4; t++) {
                    int row = row0 + i * 16 + cr + t;
                    if (row < M) P[(size_t)row * ldc + col] = acc[i][j][t];
                }
            }
    } else {
#pragma unroll
        for (int i = 0; i < 4; i++)
#pragma unroll
            for (int j = 0; j < 4; j++) {
                int col = col0 + j * 16 + cc;
                if (col >= (OUTBF ? npad : N)) continue;
                bool valid = col < N;
                float bi = (bias && valid) ? bias[col] : 0.f;
#pragma unroll
                for (int t = 0; t < 4; t++) {
                    int row = row0 + i * 16 + cr + t;
                    if (row >= M) continue;
                    float v = acc[i][j][t] + bi;
                    if (epi == 1) v = fmaxf(v, 0.f);
                    else if (epi == 2) v = ftanh(v);
                    else if (epi == 3) v = fsigmoid(v);
                    if (!valid) v = 0.f;
                    if (OUTBF) {
                        size_t idx = (iofs < 0) ? ((size_t)row * ldc + col)
                                   : ((size_t)row * ldc + ((size_t)(col >> 1) << 2) + (col & 1) + iofs);
                        ((ushort*)Cout)[idx] = f2b(v);
                    } else {
                        ((float*)Cout)[(size_t)row * ldc + col] = v;
                    }
                }
            }
    }
}

// ==== fused pair: c1=tanh(neigh1@W), c2=tanh(neigh2@W), entout=ent+c1+c2 ====
__global__ __launch_bounds__(256) void k_tanh2ent(
    const ushort* __restrict__ neigh1, const ushort* __restrict__ neigh2,
    const ushort* __restrict__ nWt, const float* __restrict__ ent,
    ushort* __restrict__ c1o, ushort* __restrict__ c2o, ushort* __restrict__ eo) {
    const int w = threadIdx.x >> 6, lane = threadIdx.x & 63;
    const int wr = w >> 1, wc = w & 1;
    const int row0 = blockIdx.x * 128 + wr * 64;
    const int col0 = wc * 64;
    const int lr = lane & 15, kg = (lane >> 4) * 8;

    f32x4 a1[4][4], a2[4][4];
#pragma unroll
    for (int i = 0; i < 4; i++)
#pragma unroll
        for (int j = 0; j < 4; j++) { a1[i][j] = (f32x4){0,0,0,0}; a2[i][j] = (f32x4){0,0,0,0}; }

    for (int kk = 0; kk < HD; kk += 32) {
        bf16x8 f1[4], f2v[4], bfr[4];
#pragma unroll
        for (int i = 0; i < 4; i++) {
            int r = min(row0 + i * 16 + lr, N_ENTS - 1);
            f1[i]  = *(const bf16x8*)(neigh1 + (size_t)r * HD + kk + kg);
            f2v[i] = *(const bf16x8*)(neigh2 + (size_t)r * HD + kk + kg);
        }
#pragma unroll
        for (int j = 0; j < 4; j++)
            bfr[j] = *(const bf16x8*)(nWt + (size_t)(col0 + j * 16 + lr) * HD + kk + kg);
#pragma unroll
        for (int i = 0; i < 4; i++)
#pragma unroll
            for (int j = 0; j < 4; j++) {
                a1[i][j] = __builtin_amdgcn_mfma_f32_16x16x32_bf16(f1[i],  bfr[j], a1[i][j], 0, 0, 0);
                a2[i][j] = __builtin_amdgcn_mfma_f32_16x16x32_bf16(f2v[i], bfr[j], a2[i][j], 0, 0, 0);
            }
    }

    const int cr = (lane >> 4) * 4, cc = lane & 15;
#pragma unroll
    for (int i = 0; i < 4; i++)
#pragma unroll
        for (int j = 0; j < 4; j++) {
            int col = col0 + j * 16 + cc;
#pragma unroll
            for (int t = 0; t < 4; t++) {
                int row = row0 + i * 16 + cr + t;
                if (row >= N_ENTS) continue;
                float t1 = ftanh(a1[i][j][t]);
                float t2 = ftanh(a2[i][j][t]);
                size_t idx = (size_t)row * HD + col;
                c1o[idx] = f2b(t1);
                c2o[idx] = f2b(t2);
                eo[idx] = f2b(ent[idx] + t1 + t2);
            }
        }
}

// ================= score GEMM: XCD-swizzled, LDS-staged NT f32x4 stores ======
__global__ __launch_bounds__(256) void k_score(
    const ushort* __restrict__ A, const ushort* __restrict__ Bt,
    const float* __restrict__ bias, float* __restrict__ C, int N) {
    __shared__ __align__(16) float st[4][16][68];
    const int w = threadIdx.x >> 6, lane = threadIdx.x & 63;
    const int lr = lane & 15, kg = (lane >> 4) * 8;
    const int cr = (lane >> 4) * 4, cc = lane & 15;
    int flat = blockIdx.y * 16 + blockIdx.x;
    int swz = (flat & 7) * 392 + (flat >> 3);         // 3136 = 8 * 392
    const int row0 = (swz & 15) * 64;
    const int colw = (swz >> 4) * 256 + w * 64;

    f32x4 acc[4][4];
#pragma unroll
    for (int i = 0; i < 4; i++)
#pragma unroll
        for (int j = 0; j < 4; j++) acc[i][j] = (f32x4){0.f, 0.f, 0.f, 0.f};

    for (int kk = 0; kk < HD; kk += 32) {
        bf16x8 af[4], bfr[4];
#pragma unroll
        for (int i = 0; i < 4; i++)
            af[i] = *(const bf16x8*)(A + (size_t)(row0 + i * 16 + lr) * HD + kk + kg);
#pragma unroll
        for (int j = 0; j < 4; j++)
            bfr[j] = *(const bf16x8*)(Bt + (size_t)(colw + j * 16 + lr) * HD + kk + kg);
#pragma unroll
        for (int i = 0; i < 4; i++)
#pragma unroll
            for (int j = 0; j < 4; j++)
                acc[i][j] = __builtin_amdgcn_mfma_f32_16x16x32_bf16(af[i], bfr[j], acc[i][j], 0, 0, 0);
    }

#pragma unroll
    for (int i = 0; i < 4; i++) {
#pragma unroll
        for (int j = 0; j < 4; j++) {
            int col = colw + j * 16 + cc;
            float bi = (col < N) ? bias[col] : 0.f;
#pragma unroll
            for (int t = 0; t < 4; t++)
                st[w][cr + t][j * 16 + cc] = fsigmoid(acc[i][j][t] + bi);
        }
#pragma unroll
        for (int p = 0; p < 4; p++) {
            int r = p * 4 + (lane >> 4);
            int cq = (lane & 15) * 4;
            f32x4 v = *(const f32x4*)&st[w][r][cq];
            int gc = colw + cq;
            if (gc < N)
                __builtin_nontemporal_store(v, (f32x4*)&C[(size_t)(row0 + i * 16 + r) * N + gc]);
        }
    }
}

// ================= fused 3-layer MLP (both MLPs via z switch) =================
__global__ __launch_bounds__(256) void k_mlp2(
    const ushort* __restrict__ A0, const ushort* __restrict__ W0t0,
    const float* __restrict__ b00, const ushort* __restrict__ W1t0,
    const float* __restrict__ b10, const float* __restrict__ w20,
    const float* __restrict__ b20, float* __restrict__ xo0,
    const ushort* __restrict__ A1, const ushort* __restrict__ W0t1,
    const float* __restrict__ b01, const ushort* __restrict__ W1t1,
    const float* __restrict__ b11, const float* __restrict__ w21,
    const float* __restrict__ b21, float* __restrict__ xo1) {
    const ushort* A   = blockIdx.z ? A1 : A0;
    const ushort* W0t = blockIdx.z ? W0t1 : W0t0;
    const float*  b0  = blockIdx.z ? b01 : b00;
    const ushort* W1t = blockIdx.z ? W1t1 : W1t0;
    const float*  b1  = blockIdx.z ? b11 : b10;
    const float*  w2  = blockIdx.z ? w21 : w20;
    const float*  b2  = blockIdx.z ? b21 : b20;
    float*        x   = blockIdx.z ? xo1 : xo0;

    __shared__ __align__(16) char lbuf[64 * 232 * 2];
    __shared__ float w2e[256], b1e[256], b0e[256];
    const int tid = threadIdx.x;
    const int w = tid >> 6, lane = tid & 63;
    const int lr = lane & 15, kg = (lane >> 4) * 8;
    const int cr = (lane >> 4) * 4, cc = lane & 15;
    const int row0 = blockIdx.x * 64;
    {
        int c = tid;
        w2e[c] = (c < HIDD) ? w2[c] : 0.f;
        b1e[c] = (c < HIDD) ? b1[c] : 0.f;
        b0e[c] = (c < HIDD) ? b0[c] : 0.f;
    }
    __syncthreads();
    ushort* g1 = (ushort*)lbuf;

    f32x4 acc[4][4];
#pragma unroll
    for (int i = 0; i < 4; i++)
#pragma unroll
        for (int j = 0; j < 4; j++) acc[i][j] = (f32x4){0.f, 0.f, 0.f, 0.f};
    for (int kk = 0; kk < 128; kk += 32) {
        bf16x8 af[4], bfr[4];
#pragma unroll
        for (int i = 0; i < 4; i++)
            af[i] = *(const bf16x8*)(A + (size_t)(row0 + i * 16 + lr) * HD + kk + kg);
#pragma unroll
        for (int j = 0; j < 4; j++)
            bfr[j] = *(const bf16x8*)(W0t + (size_t)(w * 64 + j * 16 + lr) * 128 + kk + kg);
#pragma unroll
        for (int i = 0; i < 4; i++)
#pragma unroll
            for (int j = 0; j < 4; j++)
                acc[i][j] = __builtin_amdgcn_mfma_f32_16x16x32_bf16(af[i], bfr[j], acc[i][j], 0, 0, 0);
    }
#pragma unroll
    for (int i = 0; i < 4; i++)
#pragma unroll
        for (int j = 0; j < 4; j++) {
            int col = w * 64 + j * 16 + cc;
            if (col < KPAD200) {
                float bi = b0e[col];
#pragma unroll
                for (int t = 0; t < 4; t++)
                    g1[(i * 16 + cr + t) * 232 + col] = f2b(fmaxf(acc[i][j][t] + bi, 0.f));
            }
        }
    __syncthreads();

    f32x4 a2[4][4];
#pragma unroll
    for (int i = 0; i < 4; i++)
#pragma unroll
        for (int j = 0; j < 4; j++) a2[i][j] = (f32x4){0.f, 0.f, 0.f, 0.f};
    for (int ks = 0; ks < 7; ks++) {
        int kk = ks * 32;
        bf16x8 af[4], bfr[4];
#pragma unroll
        for (int i = 0; i < 4; i++)
            af[i] = *(const bf16x8*)(g1 + (i * 16 + lr) * 232 + kk + kg);
#pragma unroll
        for (int j = 0; j < 4; j++)
            bfr[j] = *(const bf16x8*)(W1t + (size_t)(w * 64 + j * 16 + lr) * KPAD200 + kk + kg);
#pragma unroll
        for (int i = 0; i < 4; i++)
#pragma unroll
            for (int j = 0; j < 4; j++)
                a2[i][j] = __builtin_amdgcn_mfma_f32_16x16x32_bf16(af[i], bfr[j], a2[i][j], 0, 0, 0);
    }
    __syncthreads();

    float* pbuf = (float*)lbuf;   // [64][65]
#pragma unroll
    for (int i = 0; i < 4; i++)
#pragma unroll
        for (int t = 0; t < 4; t++) {
            float s = 0.f;
#pragma unroll
            for (int j = 0; j < 4; j++) {
                int col = w * 64 + j * 16 + cc;
                s += fmaxf(a2[i][j][t] + b1e[col], 0.f) * w2e[col];
            }
            pbuf[(i * 16 + cr + t) * 65 + w * 16 + cc] = s;
        }
    __syncthreads();
    if (tid < 64) {
        float s = b2[0];
        for (int q = 0; q < 64; q++) s += pbuf[tid * 65 + q];
        int gr = row0 + tid;
        if (gr < N_ENTS) x[gr] = s;
    }
}

// ================= CSR build =================
__global__ void k_deg(const int* __restrict__ dst, int* __restrict__ deg) {
    int e = blockIdx.x * 256 + threadIdx.x;
    if (e < E_EDGES) atomicAdd(&deg[dst[e]], 1);
}

__global__ void k_scan1(const int* __restrict__ in, int* __restrict__ out,
                        int* __restrict__ bsum, int n) {
    __shared__ int sh[256];
    int i = blockIdx.x * 256 + threadIdx.x;
    int v = (i < n) ? in[i] : 0;
    sh[threadIdx.x] = v; __syncthreads();
    for (int off = 1; off < 256; off <<= 1) {
        int t = (threadIdx.x >= off) ? sh[threadIdx.x - off] : 0;
        __syncthreads();
        sh[threadIdx.x] += t;
        __syncthreads();
    }
    if (i < n) out[i] = sh[threadIdx.x] - v;
    if (threadIdx.x == 255) bsum[blockIdx.x] = sh[255];
}

__global__ void k_scan2(int* __restrict__ bsum, int nb) {
    __shared__ int sh[1024];
    int t = threadIdx.x;
    int v = (t < nb) ? bsum[t] : 0;
    sh[t] = v; __syncthreads();
    for (int off = 1; off < 1024; off <<= 1) {
        int u = (t >= off) ? sh[t - off] : 0;
        __syncthreads();
        sh[t] += u;
        __syncthreads();
    }
    if (t < nb) bsum[t] = sh[t] - v;
}

__global__ void k_scan3(int* __restrict__ out, const int* __restrict__ bsum, int n) {
    int i = blockIdx.x * 256 + threadIdx.x;
    if (i < n) out[i] += bsum[blockIdx.x];
}

// fused scatter: writes sidx directly
__global__ void k_scatter2(const int* __restrict__ src, const int* __restrict__ dst,
                           const int* __restrict__ rel_id, const int* __restrict__ start,
                           int* __restrict__ cursor, int4* __restrict__ sidx) {
    int e = blockIdx.x * 256 + threadIdx.x;
    if (e < E_EDGES) {
        int n = dst[e];
        int p = start[n] + atomicAdd(&cursor[n], 1);
        sidx[p] = make_int4(src[e], n, rel_id[e], e);
    }
}

// ====== edge scores: 8 lanes/edge, granule-major => 128B-contiguous loads ======
__global__ __launch_bounds__(256) void k_scores(
    const int4* __restrict__ sidx, const ushort* __restrict__ ep,
    const ushort* __restrict__ rel, float2* __restrict__ sc) {
    int gg = threadIdx.x >> 3, l = threadIdx.x & 7;
    int slot = blockIdx.x * 32 + gg;
    int4 si = sidx[slot];
    const ushort* rs = ep + (size_t)si.x * 256;
    const ushort* rd = ep + (size_t)si.y * 256;
    const ushort* rr = rel + (size_t)si.z * 128;
    u16x8 sv[4], dv[4];
    uint2 rv[4];
#pragma unroll
    for (int i = 0; i < 4; i++) {
        int t = i * 8 + l;                       // granule 0..31
        sv[i] = *(const u16x8*)(rs + t * 8);     // lanes contiguous: 128B/edge/instr
        dv[i] = *(const u16x8*)(rd + t * 8);
        rv[i] = *(const uint2*)(rr + t * 4);
    }
    float a = 0.f, b = 0.f;
#pragma unroll
    for (int i = 0; i < 4; i++) {
        float r0 = b2f((ushort)(rv[i].x & 0xffffu)), r1 = b2f((ushort)(rv[i].x >> 16));
        float r2 = b2f((ushort)(rv[i].y & 0xffffu)), r3 = b2f((ushort)(rv[i].y >> 16));
        a += b2f(sv[i][0]) * r0 * b2f(dv[i][0]) + b2f(sv[i][1]) * r1 * b2f(dv[i][1])
           + b2f(sv[i][4]) * r2 * b2f(dv[i][4]) + b2f(sv[i][5]) * r3 * b2f(dv[i][5]);
        b += b2f(sv[i][2]) * r0 * b2f(dv[i][2]) + b2f(sv[i][3]) * r1 * b2f(dv[i][3])
           + b2f(sv[i][6]) * r2 * b2f(dv[i][6]) + b2f(sv[i][7]) * r3 * b2f(dv[i][7]);
    }
#pragma unroll
    for (int m = 4; m; m >>= 1) { a += __shfl_xor(a, m, 8); b += __shfl_xor(b, m, 8); }
    if (l == 0) sc[slot] = make_float2(a, b);
}

// ===== softmax + top-15: 16 lanes/node; d<=15 fast path; tie-break by edge id =====
__global__ __launch_bounds__(256) void k_softtop(
    const int* __restrict__ start, const int* __restrict__ deg,
    const int4* __restrict__ sidx, const float2* __restrict__ sc, float2* __restrict__ w) {
    int n = blockIdx.x * 16 + (threadIdx.x >> 4);
    int l = threadIdx.x & 15;
    if (n >= N_ENTS) return;
    int b = start[n], d = deg[n];
    if (d == 0) return;
    float m1 = -INFINITY, m2 = -INFINITY;
    for (int i = l; i < d; i += 16) {
        float2 s = sc[b + i];
        m1 = fmaxf(m1, s.x); m2 = fmaxf(m2, s.y);
    }
#pragma unroll
    for (int o = 8; o; o >>= 1) { m1 = fmaxf(m1, __shfl_xor(m1, o, 16)); m2 = fmaxf(m2, __shfl_xor(m2, o, 16)); }
    float z1 = 0.f, z2 = 0.f;
    for (int i = l; i < d; i += 16) {
        float2 s = sc[b + i];
        z1 += fexp2((s.x - m1) * L2E); z2 += fexp2((s.y - m2) * L2E);
    }
#pragma unroll
    for (int o = 8; o; o >>= 1) { z1 += __shfl_xor(z1, o, 16); z2 += __shfl_xor(z2, o, 16); }
    float iz1 = frcp(z1), iz2 = frcp(z2);
    if (d <= TOPK_K) {                 // no pruning possible: all edges kept
        for (int i = l; i < d; i += 16) {
            float2 sp = sc[b + i];
            w[b + i] = make_float2(fexp2((sp.x - m1) * L2E) * iz1,
                                   fexp2((sp.y - m2) * L2E) * iz2);
        }
        return;
    }
    for (int i = l; i < d; i += 16) {
        float2 sp = sc[b + i];
        int ei = sidx[b + i].w;
        int r1 = 0, r2 = 0;
        for (int j = 0; j < d; j++) {
            float2 sq = sc[b + j];
            int ej = sidx[b + j].w;
            r1 += (sq.x > sp.x) || (sq.x == sp.x && ej < ei);
            r2 += (sq.y > sp.y) || (sq.y == sp.y && ej < ei);
        }
        w[b + i] = make_float2(r1 < TOPK_K ? fexp2((sp.x - m1) * L2E) * iz1 : 0.f,
                               r2 < TOPK_K ? fexp2((sp.y - m2) * L2E) * iz2 : 0.f);
    }
}

// ====== weighted aggregation: block-per-node, 4 waves, 4 gather chains/wave ======
__global__ __launch_bounds__(256) void k_agg(
    const int4* __restrict__ sidx, const int* __restrict__ start, const int* __restrict__ deg,
    const float2* __restrict__ w, const ushort* __restrict__ ep, const ushort* __restrict__ rel,
    ushort* __restrict__ neigh1, ushort* __restrict__ neigh2) {
    __shared__ float4 part[3][64];
    int n = blockIdx.x;
    int wid = threadIdx.x >> 6, g = threadIdx.x & 63;
    int b = start[n], end = b + deg[n];
    float2 p1a = {0.f, 0.f}, p2a = {0.f, 0.f}, p1b = {0.f, 0.f}, p2b = {0.f, 0.f};
    for (int s = b + wid; s < end; s += 16) {
        int sB = s + 4, sC = s + 8, sD = s + 12;
        bool hB = sB < end, hC = sC < end, hD = sD < end;
        int4 siA = sidx[s];
        int4 siB = hB ? sidx[sB] : siA;
        int4 siC = hC ? sidx[sC] : siA;
        int4 siD = hD ? sidx[sD] : siA;
        float2 wA = w[s];
        float2 wB = hB ? w[sB] : make_float2(0.f, 0.f);
        float2 wC = hC ? w[sC] : make_float2(0.f, 0.f);
        float2 wD = hD ? w[sD] : make_float2(0.f, 0.f);
        u16x4 vA = *(const u16x4*)(ep + (size_t)siA.x * 256 + g * 4);
        u16x4 vB = *(const u16x4*)(ep + (size_t)siB.x * 256 + g * 4);
        u16x4 vC = *(const u16x4*)(ep + (size_t)siC.x * 256 + g * 4);
        u16x4 vD = *(const u16x4*)(ep + (size_t)siD.x * 256 + g * 4);
        uint rA = *(const uint*)(rel + (size_t)siA.z * 128 + g * 2);
        uint rB = *(const uint*)(rel + (size_t)siB.z * 128 + g * 2);
        uint rC = *(const uint*)(rel + (size_t)siC.z * 128 + g * 2);
        uint rD = *(const uint*)(rel + (size_t)siD.z * 128 + g * 2);
        float rx, ry;
        rx = b2f((ushort)(rA & 0xffffu)); ry = b2f((ushort)(rA >> 16));
        p1a.x += wA.x * b2f(vA[0]) * rx;  p1a.y += wA.x * b2f(vA[1]) * ry;
        p2a.x += wA.y * b2f(vA[2]) * rx;  p2a.y += wA.y * b2f(vA[3]) * ry;
        rx = b2f((ushort)(rB & 0xffffu)); ry = b2f((ushort)(rB >> 16));
        p1b.x += wB.x * b2f(vB[0]) * rx;  p1b.y += wB.x * b2f(vB[1]) * ry;
        p2b.x += wB.y * b2f(vB[2]) * rx;  p2b.y += wB.y * b2f(vB[3]) * ry;
        rx = b2f((ushort)(rC & 0xffffu)); ry = b2f((ushort)(rC >> 16));
        p1a.x += wC.x * b2f(vC[0]) * rx;  p1a.y += wC.x * b2f(vC[1]) * ry;
        p2a.x += wC.y * b2f(vC[2]) * rx;  p2a.y += wC.y * b2f(vC[3]) * ry;
        rx = b2f((ushort)(rD & 0xffffu)); ry = b2f((ushort)(rD >> 16));
        p1b.x += wD.x * b2f(vD[0]) * rx;  p1b.y += wD.x * b2f(vD[1]) * ry;
        p2b.x += wD.y * b2f(vD[2]) * rx;  p2b.y += wD.y * b2f(vD[3]) * ry;
    }
    float2 a1 = make_float2(p1a.x + p1b.x, p1a.y + p1b.y);
    float2 a2 = make_float2(p2a.x + p2b.x, p2a.y + p2b.y);
    if (wid > 0) part[wid - 1][g] = make_float4(a1.x, a1.y, a2.x, a2.y);
    __syncthreads();
    if (wid == 0) {
#pragma unroll
        for (int k = 0; k < 3; k++) {
            float4 p = part[k][g];
            a1.x += p.x; a1.y += p.y; a2.x += p.z; a2.y += p.w;
        }
        uint o1 = (uint)f2b(a1.x) | ((uint)f2b(a1.y) << 16);
        uint o2 = (uint)f2b(a2.x) | ((uint)f2b(a2.y) << 16);
        ((uint*)(neigh1 + (size_t)n * HD))[g] = o1;
        ((uint*)(neigh2 + (size_t)n * HD))[g] = o2;
    }
}

// ================= corr (merged, one block) =================
__global__ void k_corr(const float* __restrict__ x1, const float* __restrict__ x2,
                       float* __restrict__ out) {
    __shared__ float sa[1024], sb[1024], sc_[1024];
    int t = threadIdx.x;
    float s1 = 0.f, s2 = 0.f;
    for (int i = t; i < N_ENTS; i += 1024) { s1 += x1[i]; s2 += x2[i]; }
    sa[t] = s1; sb[t] = s2; __syncthreads();
    for (int o = 512; o > 0; o >>= 1) {
        if (t < o) { sa[t] += sa[t + o]; sb[t] += sb[t + o]; }
        __syncthreads();
    }
    float m1 = sa[0] / (float)N_ENTS, m2 = sb[0] / (float)N_ENTS;
    __syncthreads();
    float a11 = 0.f, a22 = 0.f, a12 = 0.f;
    for (int i = t; i < N_ENTS; i += 1024) {
        float a = x1[i] - m1, b = x2[i] - m2;
        a11 += a * a; a22 += b * b; a12 += a * b;
    }
    sa[t] = a11; sb[t] = a22; sc_[t] = a12; __syncthreads();
    for (int o = 512; o > 0; o >>= 1) {
        if (t < o) { sa[t] += sa[t + o]; sb[t] += sb[t + o]; sc_[t] += sc_[t + o]; }
        __syncthreads();
    }
    if (t == 0) {
        float v11 = sa[0] / (float)N_ENTS, v22 = sb[0] / (float)N_ENTS, v12 = sc_[0] / (float)N_ENTS;
        out[0] = fabsf(v12) / (sqrtf(v11) * sqrtf(v22));
    }
}

// ====== ConvE conv: fixed-channel threads, filter in regs, LDS out staging ======
__global__ __launch_bounds__(192) void k_conv(
    const int* __restrict__ h_id, const int* __restrict__ r_id,
    const ushort* __restrict__ entout, const ushort* __restrict__ prel,
    const float* __restrict__ cw, const float* __restrict__ cb,
    ushort* __restrict__ out) {
    __shared__ float img[256];
    __shared__ ushort lout[FLATD];      // 19.2 KB
    int b = blockIdx.x, tid = threadIdx.x;
    for (int i = tid; i < 256; i += 192) {
        img[i] = (i < 128) ? b2f(entout[(size_t)h_id[b] * HD + i])
                           : b2f(prel[(size_t)r_id[b] * HD + (i - 128)]);
    }
    const int o = tid >> 1, jp = tid & 1;   // channel 0..95, j-half 0..1
    float f[49];
#pragma unroll
    for (int k = 0; k < 49; k++) f[k] = cw[o * 49 + k];
    const float bi = cb[o];
    __syncthreads();
    for (int i = 0; i < 10; i++) {
#pragma unroll
        for (int jj = 0; jj < 5; jj++) {
            int j = jp * 5 + jj;
            float acc = bi;
#pragma unroll
            for (int ki = 0; ki < 7; ki++)
#pragma unroll
                for (int kj = 0; kj < 7; kj++)
                    acc += img[(i + ki) * 16 + (j + kj)] * f[ki * 7 + kj];
            lout[o * 100 + i * 10 + j] = f2b(fmaxf(acc, 0.f));
        }
    }
    __syncthreads();
    uint* go = (uint*)(out + (size_t)b * FLATD);
    const uint* lo = (const uint*)lout;
    for (int idx = tid; idx < FLATD / 2; idx += 192) go[idx] = lo[idx];
}

// ================= split-K reduce for fc =================
__global__ void k_fcreduce(const float* __restrict__ part, const float* __restrict__ bias,
                           ushort* __restrict__ out) {
    int i = blockIdx.x * 256 + threadIdx.x;
    if (i >= BSZ * HD) return;
    float s = 0.f;
    for (int z = 0; z < SPLITK; z++) s += part[(size_t)z * BSZ * HD + i];
    s += bias[i & (HD - 1)];
    out[i] = f2b(fmaxf(s, 0.f));
}

// ================= host launcher =================
extern "C" void kernel_launch(void* const* d_in, const int* in_sizes, int n_in,
                              void* d_out, int out_size, void* d_ws, size_t ws_size,
                              hipStream_t stream) {
    const int* h_id    = (const int*)d_in[0];
    const int* r_id    = (const int*)d_in[1];
    const int* src     = (const int*)d_in[2];
    const int* dst     = (const int*)d_in[3];
    const int* rel_id  = (const int*)d_in[4];
    const float* ent_emb  = (const float*)d_in[5];
    const float* rel_emb0 = (const float*)d_in[6];
    const float* neigh_w  = (const float*)d_in[7];
    const float* S_w = (const float*)d_in[8];
    const float* S_b = (const float*)d_in[9];
    const float* L_w = (const float*)d_in[10];
    const float* L_b = (const float*)d_in[11];
    const float* pred_rel = (const float*)d_in[12];
    const float* phi_w0 = (const float*)d_in[13]; const float* phi_b0 = (const float*)d_in[14];
    const float* phi_w1 = (const float*)d_in[15]; const float* phi_b1 = (const float*)d_in[16];
    const float* phi_w2 = (const float*)d_in[17]; const float* phi_b2 = (const float*)d_in[18];
    const float* psi_w0 = (const float*)d_in[19]; const float* psi_b0 = (const float*)d_in[20];
    const float* psi_w1 = (const float*)d_in[21]; const float* psi_b1 = (const float*)d_in[22];
    const float* psi_w2 = (const float*)d_in[23]; const float* psi_b2 = (const float*)d_in[24];
    const float* conv_w = (const float*)d_in[25]; const float* conv_b = (const float*)d_in[26];
    const float* fc_w   = (const float*)d_in[27]; const float* fc_b   = (const float*)d_in[28];
    const float* score_b= (const float*)d_in[29];

    char* base = (char*)d_ws;
    ushort* ep       = (ushort*)(base + OFF_EP);
    ushort* entout_bf= (ushort*)(base + OFF_ENTOUT);
    ushort* rel_bf   = (ushort*)(base + OFF_RELBF);
    ushort* prel_bf  = (ushort*)(base + OFF_PRELBF);
    ushort* Swt      = (ushort*)(base + OFF_SWT);
    ushort* Lwt      = (ushort*)(base + OFF_LWT);
    ushort* nWt      = (ushort*)(base + OFF_NWT);
    ushort* p0t      = (ushort*)(base + OFF_P0T);
    ushort* q0t      = (ushort*)(base + OFF_Q0T);
    ushort* p1t      = (ushort*)(base + OFF_P1T);
    ushort* q1t      = (ushort*)(base + OFF_Q1T);
    ushort* fct      = (ushort*)(base + OFF_FCT);
    float2* sc       = (float2*)(base + OFF_SC);
    float2* wpair    = (float2*)(base + OFF_W);
    int4*   sidx     = (int4*)(base + OFF_SIDX);
    int*    deg      = (int*)(base + OFF_DEG);
    int*    startp   = (int*)(base + OFF_START);
    int*    cursor   = (int*)(base + OFF_CUR);
    int*    bsum     = (int*)(base + OFF_BSUM);
    float*  x1       = (float*)(base + OFF_X1);
    float*  x2       = (float*)(base + OFF_X2);
    ushort* xfc_bf   = (ushort*)(base + OFF_XFC);
    ushort* c1_bf    = (ushort*)(base + OFF_EP);                 // alias (ep dead after agg)
    ushort* c2_bf    = (ushort*)(base + OFF_EP + 12812288);
    ushort* ent_bf   = (ushort*)(base + OFF_ARENA);              // temp: arena before neigh use
    ushort* neigh1_bf= (ushort*)(base + OFF_ARENA);
    ushort* neigh2_bf= (ushort*)(base + OFF_ARENA + 12812288);
    ushort* convout  = (ushort*)(base + OFF_ARENA);
    float*  fcpart   = (float*)(base + OFF_ARENA + 22421504);
    float*  outf     = (float*)d_out;

    // ---- phase 0: conversions & weight transposes (fused) ----
    k_cvt<<<dim3((MPAD * HD + 255) / 256), 256, 0, stream>>>(ent_emb, ent_bf, N_ENTS, MPAD, HD);
    k_cvt2<<<dim3(500, 1, 2), 256, 0, stream>>>(rel_emb0, rel_bf, pred_rel, prel_bf, 1000 * HD);
    k_tcvt7<<<dim3(7, 8, 7), 256, 0, stream>>>(S_w, L_w, neigh_w, phi_w0, psi_w0, phi_w1, psi_w1,
                                               Swt, Lwt, nWt, p0t, q0t, p1t, q1t);
    k_tcvtT<<<dim3(300, 4), 256, 0, stream>>>(fc_w, fct, FLATD, 128, FLATD, 128);

    // ---- phase 1: projections (fused pair) -> interleaved ep table ----
    k_mgemm<2,2,1,1><<<dim3(391, 1, 2), 256, 0, stream>>>(
        ent_bf, HD, Swt, HD, S_b, ep, 256, N_ENTS, HD, HD, HD, 0, 0, HD,
        ent_bf, Lwt, L_b, ep, 2);

    // ---- phase 2: CSR build (scatter writes sidx directly) ----
    hipMemsetAsync(deg, 0, N_ENTS * sizeof(int), stream);
    hipMemsetAsync(cursor, 0, N_ENTS * sizeof(int), stream);
    k_deg<<<dim3((E_EDGES + 255) / 256), 256, 0, stream>>>(dst, deg);
    int nscan = (N_ENTS + 255) / 256;
    k_scan1<<<dim3(nscan), 256, 0, stream>>>(deg, startp, bsum, N_ENTS);
    k_scan2<<<dim3(1), 1024, 0, stream>>>(bsum, nscan);
    k_scan3<<<dim3(nscan), 256, 0, stream>>>(startp, bsum, N_ENTS);
    k_scatter2<<<dim3((E_EDGES + 255) / 256), 256, 0, stream>>>(src, dst, rel_id, startp, cursor, sidx);

    // ---- phase 3-5: edge pipeline (split; parallelism-preserving) ----
    k_scores<<<dim3(E_EDGES / 32), 256, 0, stream>>>(sidx, ep, rel_bf, sc);
    k_softtop<<<dim3((N_ENTS + 15) / 16), 256, 0, stream>>>(startp, deg, sidx, sc, wpair);
    k_agg<<<dim3(N_ENTS), 256, 0, stream>>>(sidx, startp, deg, wpair, ep, rel_bf,
                                            neigh1_bf, neigh2_bf);

    // ---- phase 6+7: c1/c2 = tanh(neigh @ W) + ent_out, fused ----
    k_tanh2ent<<<dim3(391), 256, 0, stream>>>(neigh1_bf, neigh2_bf, nWt, ent_emb,
                                              c1_bf, c2_bf, entout_bf);

    // ---- phase 8: fused MLPs (both via z) ----
    k_mlp2<<<dim3(MPAD / 64, 1, 2), 256, 0, stream>>>(
        c1_bf, p0t, phi_b0, p1t, phi_b1, phi_w2, phi_b2, x1,
        c2_bf, q0t, psi_b0, q1t, psi_b1, psi_w2, psi_b2, x2);

    // ---- phase 9: corr (merged) ----
    k_corr<<<dim3(1), 1024, 0, stream>>>(x1, x2, outf + OUT_SCORE);

    // ---- phase 10-11: ConvE ----
    k_conv<<<dim3(BSZ), 192, 0, stream>>>(h_id, r_id, entout_bf, prel_bf, conv_w, conv_b, convout);
    k_mgemm<2,2,0,0><<<dim3(8, 1, SPLITK), 256, 0, stream>>>(
        convout, FLATD, fct, FLATD, nullptr, fcpart, HD, BSZ, HD, FLATD, FLATD / SPLITK, 0, -1, HD,
        nullptr, nullptr, nullptr, nullptr, 0);
    k_fcreduce<<<dim3((BSZ * HD + 255) / 256), 256, 0, stream>>>(fcpart, fc_b, xfc_bf);

    // ---- phase 12: score GEMM (XCD-swizzled, NT stores) ----
    k_score<<<dim3(16, 196), 256, 0, stream>>>(xfc_bf, entout_bf, score_b, outf, N_ENTS);
}